// Round 4
// baseline (549.821 us; speedup 1.0000x reference)
//
#include <hip/hip_runtime.h>
#include <math.h>

#define BATCH 8
#define CIN 512
#define COUT 256
#define HH 64
#define WW 64
#define WDIM 512

typedef __attribute__((ext_vector_type(8))) short bf16x8;
typedef __attribute__((ext_vector_type(16))) float f32x16;
typedef __attribute__((ext_vector_type(2))) float f32x2;
typedef __attribute__((ext_vector_type(4))) float f32x4;

__device__ __forceinline__ unsigned short f2bf(float f) {
    union { float f; unsigned u; } v; v.f = f;
    unsigned r = v.u + 0x7FFFu + ((v.u >> 16) & 1u);
    return (unsigned short)(r >> 16);
}

// ---------------------------------------------------------------------------
// Kernel 1: s[b,ci] = style @ (mod_weight/sqrt(512)).T + mod_bias
// Block 0 also zeros the 1KB zeropage used by conv staging.
// ---------------------------------------------------------------------------
__global__ __launch_bounds__(64)
void style_mod_kernel(const float* __restrict__ style,
                      const float* __restrict__ mod_weight,
                      const float* __restrict__ mod_bias,
                      float* __restrict__ s,
                      uint4* __restrict__ zp) {
    int idx = blockIdx.x;
    int b = idx / CIN, ci = idx % CIN;
    int lane = threadIdx.x;
    if (blockIdx.x == 0) zp[lane] = make_uint4(0u, 0u, 0u, 0u);
    const float* mw = mod_weight + (size_t)ci * WDIM;
    const float* st = style + (size_t)b * WDIM;
    float acc = 0.f;
    for (int d = lane; d < WDIM; d += 64) acc += mw[d] * st[d];
    for (int off = 32; off > 0; off >>= 1) acc += __shfl_down(acc, off);
    if (lane == 0) s[idx] = acc * 0.04419417382415922f + mod_bias[ci];
}

// ---------------------------------------------------------------------------
// Kernel 2: demod[b,co] = rsqrt(sum((scale*w*s)^2)+1e-8)
// ---------------------------------------------------------------------------
__global__ __launch_bounds__(256)
void demod_kernel(const float* __restrict__ weight,
                  const float* __restrict__ s,
                  float* __restrict__ demod) {
    int b = blockIdx.x / COUT, co = blockIdx.x % COUT;
    int t = threadIdx.x;
    const float scale = 0.014731391274719739f;
    const float* wco = weight + (size_t)co * CIN * 9;
    const float* sb = s + (size_t)b * CIN;
    float acc = 0.f;
    for (int i = t; i < CIN * 9; i += 256) {
        int ci = i / 9;
        float v = scale * wco[i] * sb[ci];
        acc += v * v;
    }
    __shared__ float red[256];
    red[t] = acc;
    __syncthreads();
    if (t < 128) red[t] += red[t + 128];
    __syncthreads();
    if (t < 64) {
        float v = red[t] + red[t + 64];
        for (int off = 32; off > 0; off >>= 1) v += __shfl_down(v, off);
        if (t == 0) demod[blockIdx.x] = rsqrtf(v + 1e-8f);
    }
}

// ---------------------------------------------------------------------------
// Kernel 3: transpose input [b][ci][y][x] fp32 -> in_t [b][y][x][ci] bf16
// ---------------------------------------------------------------------------
__global__ __launch_bounds__(256)
void transpose_kernel(const float* __restrict__ in, unsigned short* __restrict__ in_t) {
    int b = blockIdx.x >> 6, y = blockIdx.x & 63;
    __shared__ unsigned short tile[64 * 512];
    int t = threadIdx.x;
    int x = t & 63, cw = t >> 6;
    const float* src = in + (((size_t)b * CIN) * 64 + y) * 64;
    for (int it = 0; it < 128; ++it) {
        int ci = it * 4 + cw;
        float v = src[(size_t)ci * 4096 + x];
        tile[x * 512 + ((((ci >> 3) ^ (x & 7)) << 3) | (ci & 7))] = f2bf(v);
    }
    __syncthreads();
    int wv = t >> 6, lane = t & 63;
    unsigned short* dst = in_t + (((size_t)b * 64 + y) * 64) * 512;
    for (int it = 0; it < 16; ++it) {
        int xx = it * 4 + wv;
        uint4 v = *(const uint4*)&tile[xx * 512 + ((lane ^ (xx & 7)) << 3)];
        *(uint4*)(dst + (size_t)xx * 512 + lane * 8) = v;
    }
}

// ---------------------------------------------------------------------------
// Kernel 4: fold blur into modulated weights.
// W4g[b][pp=py*2+px][tap=dy*3+dx][co][ci] bf16
// ---------------------------------------------------------------------------
__global__ __launch_bounds__(256)
void fold_kernel(const float* __restrict__ weight,
                 const float* __restrict__ s,
                 const float* __restrict__ dm,
                 unsigned short* __restrict__ W4g) {
    int idx = blockIdx.x * 256 + threadIdx.x;        // b*co*ci = 1048576
    int b = idx >> 17;
    int rem = idx & 131071;
    int co = rem >> 9, ci = rem & 511;
    float m = 0.014731391274719739f * s[b * CIN + ci] * dm[b * COUT + co];
    const float* wp = weight + ((size_t)co * CIN + ci) * 9;
    float wm[3][3];
#pragma unroll
    for (int k = 0; k < 9; ++k) wm[k / 3][k % 3] = wp[k] * m;
    const float T[2][3][3] = {
        {{0.f, .25f, .75f}, {.75f, .75f, .25f}, {.25f, 0.f, 0.f}},
        {{0.f, 0.f, .25f}, {.25f, .75f, .75f}, {.75f, .25f, 0.f}}};
#pragma unroll
    for (int py = 0; py < 2; ++py)
#pragma unroll
        for (int px = 0; px < 2; ++px)
#pragma unroll
            for (int dy = 0; dy < 3; ++dy)
#pragma unroll
                for (int dx = 0; dx < 3; ++dx) {
                    float acc = 0.f;
#pragma unroll
                    for (int ky = 0; ky < 3; ++ky)
#pragma unroll
                        for (int kx = 0; kx < 3; ++kx)
                            acc += T[py][dy][ky] * T[px][dx][kx] * wm[ky][kx];
                    size_t off = ((((size_t)(b * 4 + py * 2 + px) * 9 + dy * 3 + dx) * COUT + co) * CIN) + ci;
                    W4g[off] = f2bf(acc);
                }
}

// ---------------------------------------------------------------------------
// Kernel 5: MFMA conv, 512 threads / 8 waves. wave w = output row r (8 rows).
// Each wave computes BOTH px: acc[2px][2mt][2nt] -> 6 LDS reads per 8 MFMA.
// Double-buffered global_load_lds staging, 2-phase counted-vmcnt schedule.
//
// COMPUTE is a 2-deep software pipeline over taps: tap t+1's 6 ds_read_b128
// issue BEFORE tap t's 8 MFMAs, pinned via sched_group_barrier pattern
// [R0][R1 M0][R2 M1]...[M8], so the LDS pipe and matrix pipe run
// concurrently instead of burst-alternating (the round-0..3 41% ceiling).
//
// Conflict-free slot order (h = k-half OUTER of cell/co so ds_read_b128 is
// contiguous 16B/lane per half-wave):
//   tasks    0..1319 : input  slot = (row*2+h)*66 + cell   (10 rows x 66)
//   tasks 1320..3623 : weight slot = 1320 + (tp*2+h)*64 + co (18 tp)
//   tasks 3624..4095 : dummy (zeropage) -> uniform 8 issues per wave
// Slot byte addr = task*16 (linear in task order, as DMA requires).
// ---------------------------------------------------------------------------
#define BUF_BYTES 65536                 // 4096 slots * 16B
#define LDS_W0 21120                    // 1320 * 16
#define LDS_TOTAL2 (2 * BUF_BYTES)      // 131072

__global__ __launch_bounds__(512, 2)
void conv_kernel(const unsigned short* __restrict__ in_t,
                 const unsigned short* __restrict__ W4g,
                 const uint4* __restrict__ zeropage,
                 float* __restrict__ out) {
    __shared__ char lds[LDS_TOTAL2];
    int L = blockIdx.x;                 // 512 blocks
    // XCD swizzle: 8 Y-siblings of a (b,py,cb) group spaced 8 apart -> same XCD
    int g = ((L >> 6) << 3) | (L & 7);
    int sbq = (L >> 3) & 7;
    int b = g >> 3, rgrp = g & 7;
    int py = rgrp >> 2, cb = rgrp & 3;
    int Y0 = sbq * 8;
    int t = threadIdx.x, w = t >> 6, lane = t & 63;
    int l31 = lane & 31, hf = lane >> 5;
    int r = w;                          // wave owns output row Y0 + r

    const unsigned short* inb = in_t + (size_t)b * 64 * 64 * 512;
    const unsigned short* wb = W4g + ((size_t)(b * 4 + py * 2)) * 9 * COUT * CIN;

    // per-thread static task -> 8 global byte pointers (advance 32B per chunk)
    const char* gp[8];
#pragma unroll
    for (int k = 0; k < 8; ++k) {
        int task = t + (k << 9);
        const void* p;
        if (task < 1320) {
            int row = task / 132;
            int rem = task - row * 132;
            int h = rem / 66;
            int cell = rem - h * 66;
            int y = Y0 - 1 + row, x = cell - 1;
            p = ((unsigned)y < 64u && (unsigned)x < 64u)
                    ? (const void*)(inb + ((size_t)(y * 64 + x) * 512 + h * 8))
                    : (const void*)zeropage;
        } else if (task < 3624) {
            int wt = task - 1320;
            int co = wt & 63, h = (wt >> 6) & 1, tp = wt >> 7;
            p = (const void*)(wb + (size_t)tp * (COUT * CIN) +
                              (size_t)(cb * 64 + co) * CIN + h * 8);
        } else {
            p = (const void*)zeropage;
        }
        gp[k] = (const char*)p;
    }

    f32x16 acc[2][2][2];                // [px][mt][nt]
#pragma unroll
    for (int px = 0; px < 2; ++px)
#pragma unroll
        for (int mt = 0; mt < 2; ++mt)
#pragma unroll
            for (int nt = 0; nt < 2; ++nt) acc[px][mt][nt] = (f32x16)0.f;

#define STAGE(BUFOFF)                                                             \
    {                                                                             \
        char* lb = lds + (BUFOFF) + (w << 10);                                    \
        _Pragma("unroll")                                                         \
        for (int k = 0; k < 8; ++k) {                                             \
            __builtin_amdgcn_global_load_lds(                                     \
                (const __attribute__((address_space(1))) void*)gp[k],             \
                (__attribute__((address_space(3))) void*)(lb + (k << 13)),        \
                16, 0, 0);                                                        \
            gp[k] += 32;                                                          \
        }                                                                         \
    }

#define BAR()                                  \
    {                                          \
        asm volatile("" ::: "memory");         \
        __builtin_amdgcn_s_barrier();          \
        asm volatile("" ::: "memory");         \
    }

#define SGB __builtin_amdgcn_sched_group_barrier

    // 2-deep tap pipeline. Reg sets indexed by tap parity (compile-time under
    // full unroll -> stays in registers, rule #20).
#define COMPUTE(BUFOFF)                                                             \
    {                                                                               \
        const char* Bp = lds + (BUFOFF);                                            \
        bf16x8 Ra0[2], Ra1[2], Rb[2][2][2];                                         \
        {   /* prologue: tap 0 -> parity 0 */                                       \
            int cell0 = ((1 + r - 1) * 2 + hf) * 66 + (1 + l31 - 1);                \
            Ra0[0] = *(const bf16x8*)(Bp + (cell0 << 4));                           \
            Ra1[0] = *(const bf16x8*)(Bp + ((cell0 + 32) << 4));                    \
            _Pragma("unroll")                                                       \
            for (int px = 0; px < 2; ++px) {                                        \
                int tp = px * 9;                                                    \
                const char* Wp = Bp + LDS_W0 + (((tp * 2 + hf) * 64 + l31) << 4);   \
                Rb[0][px][0] = *(const bf16x8*)(Wp);                                \
                Rb[0][px][1] = *(const bf16x8*)(Wp + 512);                          \
            }                                                                       \
        }                                                                           \
        SGB(0x100, 6, 0);                       /* [R0] */                          \
        _Pragma("unroll")                                                           \
        for (int tap = 0; tap < 9; ++tap) {                                         \
            const int cur = tap & 1, nxt = cur ^ 1;                                 \
            if (tap < 8) {                                                          \
                const int tn = tap + 1;                                             \
                const int dy = tn / 3 - 1, dx = tn % 3 - 1;                         \
                int cell0 = ((1 + r + dy) * 2 + hf) * 66 + (1 + l31 + dx);          \
                Ra0[nxt] = *(const bf16x8*)(Bp + (cell0 << 4));                     \
                Ra1[nxt] = *(const bf16x8*)(Bp + ((cell0 + 32) << 4));              \
                _Pragma("unroll")                                                   \
                for (int px = 0; px < 2; ++px) {                                    \
                    int tp = px * 9 + tn;                                           \
                    const char* Wp = Bp + LDS_W0 +                                  \
                                     (((tp * 2 + hf) * 64 + l31) << 4);             \
                    Rb[nxt][px][0] = *(const bf16x8*)(Wp);                          \
                    Rb[nxt][px][1] = *(const bf16x8*)(Wp + 512);                    \
                }                                                                   \
                SGB(0x100, 6, 0);               /* [R(t+1)] */                      \
            }                                                                       \
            _Pragma("unroll")                                                       \
            for (int px = 0; px < 2; ++px) {                                        \
                acc[px][0][0] = __builtin_amdgcn_mfma_f32_32x32x16_bf16(            \
                    Ra0[cur], Rb[cur][px][0], acc[px][0][0], 0, 0, 0);              \
                acc[px][0][1] = __builtin_amdgcn_mfma_f32_32x32x16_bf16(            \
                    Ra0[cur], Rb[cur][px][1], acc[px][0][1], 0, 0, 0);              \
                acc[px][1][0] = __builtin_amdgcn_mfma_f32_32x32x16_bf16(            \
                    Ra1[cur], Rb[cur][px][0], acc[px][1][0], 0, 0, 0);              \
                acc[px][1][1] = __builtin_amdgcn_mfma_f32_32x32x16_bf16(            \
                    Ra1[cur], Rb[cur][px][1], acc[px][1][1], 0, 0, 0);              \
            }                                                                       \
            SGB(0x8, 8, 0);                     /* [M(t)] */                        \
        }                                                                           \
    }

    STAGE(0);                                   // chunk 0 -> buf0
#pragma unroll 1
    for (int cc = 0; cc < 16; ++cc) {
        // phase A: stage chunk 2cc+1 -> buf1, compute chunk 2cc from buf0
        STAGE(BUF_BYTES);
        asm volatile("s_waitcnt vmcnt(8)" ::: "memory");
        BAR();
        __builtin_amdgcn_s_setprio(1);
        COMPUTE(0);
        __builtin_amdgcn_s_setprio(0);
        BAR();
        // phase B: stage chunk 2cc+2 -> buf0 (if any), compute chunk 2cc+1
        if (cc < 15) {
            STAGE(0);
            asm volatile("s_waitcnt vmcnt(8)" ::: "memory");
        } else {
            asm volatile("s_waitcnt vmcnt(0)" ::: "memory");
        }
        BAR();
        __builtin_amdgcn_s_setprio(1);
        COMPUTE(BUF_BYTES);
        __builtin_amdgcn_s_setprio(0);
        BAR();
    }
    __syncthreads();    // all waves done reading buffers before epilogue reuse

    // ---- epilogue: per-wave LDS transpose to (co, fx), coalesced stores ----
    float* ob = (float*)(lds + w * 9216);   // [64 co][36 floats pitch] (144B)
    int fy = 2 * (Y0 + r) + py;
    float* outb = out + (((size_t)b * COUT + cb * 64) * 128 + fy) * 128;
#pragma unroll
    for (int mt = 0; mt < 2; ++mt)
#pragma unroll
        for (int hh = 0; hh < 2; ++hh) {
            int fx0 = mt * 64 + hh * 32;
#pragma unroll
            for (int nt = 0; nt < 2; ++nt)
#pragma unroll
                for (int j = 0; j < 8; ++j) {
                    int reg = hh * 8 + j;
                    int Xl = (j & 3) + ((j >> 2) << 3) + (hf << 2);
                    int cw = nt * 32 + l31;
                    f32x2 v;
                    v.x = acc[0][mt][nt][reg];
                    v.y = acc[1][mt][nt][reg];
                    *(f32x2*)(ob + cw * 36 + Xl * 2) = v;
                }
            asm volatile("s_waitcnt lgkmcnt(0)" ::: "memory");
#pragma unroll
            for (int rr = 0; rr < 2; ++rr) {
                int co_r = (lane >> 1) + rr * 32;
                const float* srcp = ob + co_r * 36 + (lane & 1) * 16;
                float* dstp = outb + (size_t)co_r * 16384 + fx0 + (lane & 1) * 16;
#pragma unroll
                for (int q = 0; q < 4; ++q)
                    *(f32x4*)(dstp + q * 4) = *(const f32x4*)(srcp + q * 4);
            }
            asm volatile("s_waitcnt lgkmcnt(0)" ::: "memory");
        }
#undef STAGE
#undef BAR
#undef COMPUTE
}

// ---------------------------------------------------------------------------
// FALLBACK (round-1 fp32 path) if ws_size too small for the MFMA pipeline
// ---------------------------------------------------------------------------
__global__ __launch_bounds__(256)
void fused_upconv_blur_kernel(const float* __restrict__ input,
                              const float* __restrict__ weight,
                              const float* __restrict__ s,
                              const float* __restrict__ demod,
                              float* __restrict__ out) {
    const int t = threadIdx.x;
    const int tY = blockIdx.x >> 2, tX = blockIdx.x & 3;
    const int cob = blockIdx.y * 4;
    const int b = blockIdx.z;
    const int Y0 = tY * 16, X0 = tX * 16;
    __shared__ __attribute__((aligned(16))) float patch[19][20];
    __shared__ __attribute__((aligned(16))) float wsm[4][12];
    __shared__ __attribute__((aligned(16))) float out1[36][37];
    __shared__ __attribute__((aligned(16))) float tmpb[35][33];
    const float scale = 0.014731391274719739f;
    float dmv[4];
#pragma unroll
    for (int c = 0; c < 4; ++c) dmv[c] = demod[b * COUT + cob + c] * scale;
    float a0[4][4], a1[4][4];
#pragma unroll
    for (int c = 0; c < 4; ++c)
#pragma unroll
        for (int q = 0; q < 4; ++q) { a0[c][q] = 0.f; a1[c][q] = 0.f; }
    const int p0 = t, p1 = t + 256;
    const int qY0 = p0 / 18, qX0 = p0 % 18;
    const int qY1s = p1 / 18, qX1 = p1 % 18;
    const bool act1 = (p1 < 324);
    const int qY1 = act1 ? qY1s : 0;
    const float* inb = input + (size_t)b * CIN * HH * WW;
    const float* sb = s + (size_t)b * CIN;
    for (int ci = 0; ci < CIN; ++ci) {
        const float* inc = inb + (size_t)ci * (HH * WW);
        for (int idx = t; idx < 361; idx += 256) {
            int rr = idx / 19, cc = idx - rr * 19;
            int gr = Y0 - 2 + rr, gc = X0 - 2 + cc;
            float v = 0.f;
            if ((unsigned)gr < 64u && (unsigned)gc < 64u) v = inc[gr * 64 + gc];
            patch[rr][cc] = v;
        }
        if (t < 36) {
            int c = t / 9, k = t - c * 9;
            wsm[c][k] = weight[((size_t)(cob + c) * CIN + ci) * 9 + k] * sb[ci] * dmv[c];
        }
        __syncthreads();
        const float i00a = patch[qY0][qX0], i01a = patch[qY0][qX0 + 1];
        const float i10a = patch[qY0 + 1][qX0], i11a = patch[qY0 + 1][qX0 + 1];
        float i00b = 0.f, i01b = 0.f, i10b = 0.f, i11b = 0.f;
        if (act1) {
            i00b = patch[qY1][qX1]; i01b = patch[qY1][qX1 + 1];
            i10b = patch[qY1 + 1][qX1]; i11b = patch[qY1 + 1][qX1 + 1];
        }
#pragma unroll
        for (int c = 0; c < 4; ++c) {
            const float4 wA = *(const float4*)&wsm[c][0];
            const float4 wB = *(const float4*)&wsm[c][4];
            const float w8v = wsm[c][8];
            a0[c][0] += i11a * wA.x + i10a * wA.z + i01a * wB.z + i00a * w8v;
            a0[c][1] += i11a * wA.y + i01a * wB.w;
            a0[c][2] += i11a * wA.w + i10a * wB.y;
            a0[c][3] += i11a * wB.x;
            if (act1) {
                a1[c][0] += i11b * wA.x + i10b * wA.z + i01b * wB.z + i00b * w8v;
                a1[c][1] += i11b * wA.y + i01b * wB.w;
                a1[c][2] += i11b * wA.w + i10b * wB.y;
                a1[c][3] += i11b * wB.x;
            }
        }
        __syncthreads();
    }
    const size_t out_base = ((size_t)b * COUT + cob) * 128 * 128;
    for (int c = 0; c < 4; ++c) {
        __syncthreads();
        out1[2 * qY0][2 * qX0] = a0[c][0];
        out1[2 * qY0][2 * qX0 + 1] = a0[c][1];
        out1[2 * qY0 + 1][2 * qX0] = a0[c][2];
        out1[2 * qY0 + 1][2 * qX0 + 1] = a0[c][3];
        if (act1) {
            out1[2 * qY1][2 * qX1] = a1[c][0];
            out1[2 * qY1][2 * qX1 + 1] = a1[c][1];
            out1[2 * qY1 + 1][2 * qX1] = a1[c][2];
            out1[2 * qY1 + 1][2 * qX1 + 1] = a1[c][3];
        }
        __syncthreads();
        for (int idx = t; idx < 35 * 32; idx += 256) {
            int rr = idx >> 5, x = idx & 31;
            tmpb[rr][x] = 0.25f * (out1[rr + 1][x + 1] + out1[rr + 1][x + 4])
                        + 0.75f * (out1[rr + 1][x + 2] + out1[rr + 1][x + 3]);
        }
        __syncthreads();
        float* outc = out + out_base + (size_t)c * 128 * 128;
        for (int idx = t; idx < 1024; idx += 256) {
            int oy = idx >> 5, x = idx & 31;
            float v = 0.25f * (tmpb[oy][x] + tmpb[oy + 3][x])
                    + 0.75f * (tmpb[oy + 1][x] + tmpb[oy + 2][x]);
            outc[(size_t)(2 * Y0 + oy) * 128 + (2 * X0 + x)] = v;
        }
    }
}

// ---------------------------------------------------------------------------
extern "C" void kernel_launch(void* const* d_in, const int* in_sizes, int n_in,
                              void* d_out, int out_size, void* d_ws, size_t ws_size,
                              hipStream_t stream) {
    const float* input      = (const float*)d_in[0];
    const float* style      = (const float*)d_in[1];
    const float* weight     = (const float*)d_in[2];
    const float* mod_weight = (const float*)d_in[3];
    const float* mod_bias   = (const float*)d_in[4];
    float* out = (float*)d_out;

    // ws layout: s(16KB) | dm(8KB) | zeropage(1KB)+pad | in_t bf16 | W4g bf16
    const size_t OFF_S = 0, OFF_DM = 16384, OFF_ZP = 24576, OFF_INT = 32768;
    const size_t OFF_W4 = OFF_INT + (size_t)BATCH * 64 * 64 * CIN * 2;      // 33587200
    const size_t WS_NEEDED = OFF_W4 + (size_t)BATCH * 4 * 9 * COUT * CIN * 2; // 109084672

    float* s_buf  = (float*)((char*)d_ws + OFF_S);
    float* dm_buf = (float*)((char*)d_ws + OFF_DM);
    uint4* zp     = (uint4*)((char*)d_ws + OFF_ZP);

    style_mod_kernel<<<BATCH * CIN, 64, 0, stream>>>(style, mod_weight, mod_bias, s_buf, zp);
    demod_kernel<<<BATCH * COUT, 256, 0, stream>>>(weight, s_buf, dm_buf);

    if (ws_size >= WS_NEEDED) {
        unsigned short* in_t = (unsigned short*)((char*)d_ws + OFF_INT);
        unsigned short* W4g  = (unsigned short*)((char*)d_ws + OFF_W4);
        transpose_kernel<<<BATCH * 64, 256, 0, stream>>>(input, in_t);
        fold_kernel<<<(BATCH * COUT * CIN) / 256, 256, 0, stream>>>(weight, s_buf, dm_buf, W4g);
        conv_kernel<<<512, 512, 0, stream>>>(in_t, W4g, zp, out);
    } else {
        fused_upconv_blur_kernel<<<dim3(16, COUT / 4, BATCH), 256, 0, stream>>>(
            input, weight, s_buf, dm_buf, out);
    }
}

// Round 5
// 519.295 us; speedup vs baseline: 1.0588x; 1.0588x over previous
//
#include <hip/hip_runtime.h>
#include <math.h>

#define BATCH 8
#define CIN 512
#define COUT 256
#define HH 64
#define WW 64
#define WDIM 512

typedef __attribute__((ext_vector_type(8))) short bf16x8;
typedef __attribute__((ext_vector_type(16))) float f32x16;
typedef __attribute__((ext_vector_type(2))) float f32x2;
typedef __attribute__((ext_vector_type(4))) float f32x4;

__device__ __forceinline__ unsigned short f2bf(float f) {
    union { float f; unsigned u; } v; v.f = f;
    unsigned r = v.u + 0x7FFFu + ((v.u >> 16) & 1u);
    return (unsigned short)(r >> 16);
}

// ---------------------------------------------------------------------------
// Kernel 1: s[b,ci] = style @ (mod_weight/sqrt(512)).T + mod_bias
// Block 0 also zeros the 1KB zeropage used by conv staging.
// ---------------------------------------------------------------------------
__global__ __launch_bounds__(64)
void style_mod_kernel(const float* __restrict__ style,
                      const float* __restrict__ mod_weight,
                      const float* __restrict__ mod_bias,
                      float* __restrict__ s,
                      uint4* __restrict__ zp) {
    int idx = blockIdx.x;
    int b = idx / CIN, ci = idx % CIN;
    int lane = threadIdx.x;
    if (blockIdx.x == 0) zp[lane] = make_uint4(0u, 0u, 0u, 0u);
    const float* mw = mod_weight + (size_t)ci * WDIM;
    const float* st = style + (size_t)b * WDIM;
    float acc = 0.f;
    for (int d = lane; d < WDIM; d += 64) acc += mw[d] * st[d];
    for (int off = 32; off > 0; off >>= 1) acc += __shfl_down(acc, off);
    if (lane == 0) s[idx] = acc * 0.04419417382415922f + mod_bias[ci];
}

// ---------------------------------------------------------------------------
// Kernel 2: demod[b,co] = rsqrt(sum((scale*w*s)^2)+1e-8)
// ---------------------------------------------------------------------------
__global__ __launch_bounds__(256)
void demod_kernel(const float* __restrict__ weight,
                  const float* __restrict__ s,
                  float* __restrict__ demod) {
    int b = blockIdx.x / COUT, co = blockIdx.x % COUT;
    int t = threadIdx.x;
    const float scale = 0.014731391274719739f;
    const float* wco = weight + (size_t)co * CIN * 9;
    const float* sb = s + (size_t)b * CIN;
    float acc = 0.f;
    for (int i = t; i < CIN * 9; i += 256) {
        int ci = i / 9;
        float v = scale * wco[i] * sb[ci];
        acc += v * v;
    }
    __shared__ float red[256];
    red[t] = acc;
    __syncthreads();
    if (t < 128) red[t] += red[t + 128];
    __syncthreads();
    if (t < 64) {
        float v = red[t] + red[t + 64];
        for (int off = 32; off > 0; off >>= 1) v += __shfl_down(v, off);
        if (t == 0) demod[blockIdx.x] = rsqrtf(v + 1e-8f);
    }
}

// ---------------------------------------------------------------------------
// Kernel 3: transpose input [b][ci][y][x] fp32 -> in_t [b][y][x][ci] bf16
// ---------------------------------------------------------------------------
__global__ __launch_bounds__(256)
void transpose_kernel(const float* __restrict__ in, unsigned short* __restrict__ in_t) {
    int b = blockIdx.x >> 6, y = blockIdx.x & 63;
    __shared__ unsigned short tile[64 * 512];
    int t = threadIdx.x;
    int x = t & 63, cw = t >> 6;
    const float* src = in + (((size_t)b * CIN) * 64 + y) * 64;
    for (int it = 0; it < 128; ++it) {
        int ci = it * 4 + cw;
        float v = src[(size_t)ci * 4096 + x];
        tile[x * 512 + ((((ci >> 3) ^ (x & 7)) << 3) | (ci & 7))] = f2bf(v);
    }
    __syncthreads();
    int wv = t >> 6, lane = t & 63;
    unsigned short* dst = in_t + (((size_t)b * 64 + y) * 64) * 512;
    for (int it = 0; it < 16; ++it) {
        int xx = it * 4 + wv;
        uint4 v = *(const uint4*)&tile[xx * 512 + ((lane ^ (xx & 7)) << 3)];
        *(uint4*)(dst + (size_t)xx * 512 + lane * 8) = v;
    }
}

// ---------------------------------------------------------------------------
// Kernel 4 (REWRITTEN for write coalescing): fold blur into modulated weights.
// W4g[b][pp=py*2+px][tap=dy*3+dx][co][ci] bf16 — layout unchanged.
//
// Old version: thread per (b,co,ci), 36 scattered 2-B stores (each its own
// cache line, ~128KB apart) -> write-coalescing disaster on 75.5 MB.
// New version: block = (b, co-pair); thread = (co_local = t>>7, ci0 = (t&127)*4).
// Reads 4ci x 9 floats = 144 B contiguous per thread (contiguous across
// threads); writes each (pp,tap) as one ushort4 (8 B), fully contiguous
// across the 128-thread ci-group -> every store instruction covers 1 KB/wave.
// ---------------------------------------------------------------------------
__global__ __launch_bounds__(256)
void fold_kernel(const float* __restrict__ weight,
                 const float* __restrict__ s,
                 const float* __restrict__ dm,
                 unsigned short* __restrict__ W4g) {
    int b = blockIdx.x >> 7;            // 8 batches
    int cop = blockIdx.x & 127;         // 128 co-pairs
    int t = threadIdx.x;
    int co = cop * 2 + (t >> 7);
    int ci0 = (t & 127) * 4;

    float dmv = 0.014731391274719739f * dm[b * COUT + co];
    const float* wp = weight + ((size_t)co * CIN + ci0) * 9;

    float wm[4][9];
#pragma unroll
    for (int c = 0; c < 4; ++c) {
        float m = s[b * CIN + ci0 + c] * dmv;
#pragma unroll
        for (int k = 0; k < 9; ++k) wm[c][k] = wp[c * 9 + k] * m;
    }

    // T[p][d'][wi]: blur folded per-dim transfer (d' = -1..1 -> 0..2)
    const float T[2][3][3] = {
        {{0.f, .25f, .75f}, {.75f, .75f, .25f}, {.25f, 0.f, 0.f}},
        {{0.f, 0.f, .25f}, {.25f, .75f, .75f}, {.75f, .25f, 0.f}}};

#pragma unroll
    for (int py = 0; py < 2; ++py)
#pragma unroll
        for (int px = 0; px < 2; ++px)
#pragma unroll
            for (int dy = 0; dy < 3; ++dy)
#pragma unroll
                for (int dx = 0; dx < 3; ++dx) {
                    unsigned short pk[4];
#pragma unroll
                    for (int c = 0; c < 4; ++c) {
                        float acc = 0.f;
#pragma unroll
                        for (int ky = 0; ky < 3; ++ky)
#pragma unroll
                            for (int kx = 0; kx < 3; ++kx)
                                acc += T[py][dy][ky] * T[px][dx][kx] * wm[c][ky * 3 + kx];
                        pk[c] = f2bf(acc);
                    }
                    size_t off = ((((size_t)(b * 4 + py * 2 + px) * 9 + dy * 3 + dx) * COUT + co) * CIN) + ci0;
                    ushort4 v; v.x = pk[0]; v.y = pk[1]; v.z = pk[2]; v.w = pk[3];
                    *(ushort4*)(W4g + off) = v;
                }
}

// ---------------------------------------------------------------------------
// Kernel 5: MFMA conv, 512 threads / 8 waves. wave w = output row r (8 rows).
// Each wave computes BOTH px: acc[2px][2mt][2nt] -> 6 LDS reads per 8 MFMA.
// Double-buffered global_load_lds staging, 2-phase counted-vmcnt schedule.
// (Unchanged from round 4 — conv is at its LDS/MFMA serialization plateau.)
// ---------------------------------------------------------------------------
#define BUF_BYTES 65536                 // 4096 slots * 16B
#define LDS_W0 21120                    // 1320 * 16
#define LDS_TOTAL2 (2 * BUF_BYTES)      // 131072

__global__ __launch_bounds__(512, 2)
void conv_kernel(const unsigned short* __restrict__ in_t,
                 const unsigned short* __restrict__ W4g,
                 const uint4* __restrict__ zeropage,
                 float* __restrict__ out) {
    __shared__ char lds[LDS_TOTAL2];
    int L = blockIdx.x;                 // 512 blocks
    // XCD swizzle: 8 Y-siblings of a (b,py,cb) group spaced 8 apart -> same XCD
    int g = ((L >> 6) << 3) | (L & 7);
    int sbq = (L >> 3) & 7;
    int b = g >> 3, rgrp = g & 7;
    int py = rgrp >> 2, cb = rgrp & 3;
    int Y0 = sbq * 8;
    int t = threadIdx.x, w = t >> 6, lane = t & 63;
    int l31 = lane & 31, hf = lane >> 5;
    int r = w;                          // wave owns output row Y0 + r

    const unsigned short* inb = in_t + (size_t)b * 64 * 64 * 512;
    const unsigned short* wb = W4g + ((size_t)(b * 4 + py * 2)) * 9 * COUT * CIN;

    // per-thread static task -> 8 global byte pointers (advance 32B per chunk)
    const char* gp[8];
#pragma unroll
    for (int k = 0; k < 8; ++k) {
        int task = t + (k << 9);
        const void* p;
        if (task < 1320) {
            int row = task / 132;
            int rem = task - row * 132;
            int h = rem / 66;
            int cell = rem - h * 66;
            int y = Y0 - 1 + row, x = cell - 1;
            p = ((unsigned)y < 64u && (unsigned)x < 64u)
                    ? (const void*)(inb + ((size_t)(y * 64 + x) * 512 + h * 8))
                    : (const void*)zeropage;
        } else if (task < 3624) {
            int wt = task - 1320;
            int co = wt & 63, h = (wt >> 6) & 1, tp = wt >> 7;
            p = (const void*)(wb + (size_t)tp * (COUT * CIN) +
                              (size_t)(cb * 64 + co) * CIN + h * 8);
        } else {
            p = (const void*)zeropage;
        }
        gp[k] = (const char*)p;
    }

    f32x16 acc[2][2][2];                // [px][mt][nt]
#pragma unroll
    for (int px = 0; px < 2; ++px)
#pragma unroll
        for (int mt = 0; mt < 2; ++mt)
#pragma unroll
            for (int nt = 0; nt < 2; ++nt) acc[px][mt][nt] = (f32x16)0.f;

#define STAGE(BUFOFF)                                                             \
    {                                                                             \
        char* lb = lds + (BUFOFF) + (w << 10);                                    \
        _Pragma("unroll")                                                         \
        for (int k = 0; k < 8; ++k) {                                             \
            __builtin_amdgcn_global_load_lds(                                     \
                (const __attribute__((address_space(1))) void*)gp[k],             \
                (__attribute__((address_space(3))) void*)(lb + (k << 13)),        \
                16, 0, 0);                                                        \
            gp[k] += 32;                                                          \
        }                                                                         \
    }

#define BAR()                                  \
    {                                          \
        asm volatile("" ::: "memory");         \
        __builtin_amdgcn_s_barrier();          \
        asm volatile("" ::: "memory");         \
    }

#define SGB __builtin_amdgcn_sched_group_barrier

    // 2-deep tap pipeline. Reg sets indexed by tap parity (compile-time under
    // full unroll -> stays in registers, rule #20).
#define COMPUTE(BUFOFF)                                                             \
    {                                                                               \
        const char* Bp = lds + (BUFOFF);                                            \
        bf16x8 Ra0[2], Ra1[2], Rb[2][2][2];                                         \
        {   /* prologue: tap 0 -> parity 0 */                                       \
            int cell0 = ((1 + r - 1) * 2 + hf) * 66 + (1 + l31 - 1);                \
            Ra0[0] = *(const bf16x8*)(Bp + (cell0 << 4));                           \
            Ra1[0] = *(const bf16x8*)(Bp + ((cell0 + 32) << 4));                    \
            _Pragma("unroll")                                                       \
            for (int px = 0; px < 2; ++px) {                                        \
                int tp = px * 9;                                                    \
                const char* Wp = Bp + LDS_W0 + (((tp * 2 + hf) * 64 + l31) << 4);   \
                Rb[0][px][0] = *(const bf16x8*)(Wp);                                \
                Rb[0][px][1] = *(const bf16x8*)(Wp + 512);                          \
            }                                                                       \
        }                                                                           \
        SGB(0x100, 6, 0);                       /* [R0] */                          \
        _Pragma("unroll")                                                           \
        for (int tap = 0; tap < 9; ++tap) {                                         \
            const int cur = tap & 1, nxt = cur ^ 1;                                 \
            if (tap < 8) {                                                          \
                const int tn = tap + 1;                                             \
                const int dy = tn / 3 - 1, dx = tn % 3 - 1;                         \
                int cell0 = ((1 + r + dy) * 2 + hf) * 66 + (1 + l31 + dx);          \
                Ra0[nxt] = *(const bf16x8*)(Bp + (cell0 << 4));                     \
                Ra1[nxt] = *(const bf16x8*)(Bp + ((cell0 + 32) << 4));              \
                _Pragma("unroll")                                                   \
                for (int px = 0; px < 2; ++px) {                                    \
                    int tp = px * 9 + tn;                                           \
                    const char* Wp = Bp + LDS_W0 +                                  \
                                     (((tp * 2 + hf) * 64 + l31) << 4);             \
                    Rb[nxt][px][0] = *(const bf16x8*)(Wp);                          \
                    Rb[nxt][px][1] = *(const bf16x8*)(Wp + 512);                    \
                }                                                                   \
                SGB(0x100, 6, 0);               /* [R(t+1)] */                      \
            }                                                                       \
            _Pragma("unroll")                                                       \
            for (int px = 0; px < 2; ++px) {                                        \
                acc[px][0][0] = __builtin_amdgcn_mfma_f32_32x32x16_bf16(            \
                    Ra0[cur], Rb[cur][px][0], acc[px][0][0], 0, 0, 0);              \
                acc[px][0][1] = __builtin_amdgcn_mfma_f32_32x32x16_bf16(            \
                    Ra0[cur], Rb[cur][px][1], acc[px][0][1], 0, 0, 0);              \
                acc[px][1][0] = __builtin_amdgcn_mfma_f32_32x32x16_bf16(            \
                    Ra1[cur], Rb[cur][px][0], acc[px][1][0], 0, 0, 0);              \
                acc[px][1][1] = __builtin_amdgcn_mfma_f32_32x32x16_bf16(            \
                    Ra1[cur], Rb[cur][px][1], acc[px][1][1], 0, 0, 0);              \
            }                                                                       \
            SGB(0x8, 8, 0);                     /* [M(t)] */                        \
        }                                                                           \
    }

    STAGE(0);                                   // chunk 0 -> buf0
#pragma unroll 1
    for (int cc = 0; cc < 16; ++cc) {
        // phase A: stage chunk 2cc+1 -> buf1, compute chunk 2cc from buf0
        STAGE(BUF_BYTES);
        asm volatile("s_waitcnt vmcnt(8)" ::: "memory");
        BAR();
        __builtin_amdgcn_s_setprio(1);
        COMPUTE(0);
        __builtin_amdgcn_s_setprio(0);
        BAR();
        // phase B: stage chunk 2cc+2 -> buf0 (if any), compute chunk 2cc+1
        if (cc < 15) {
            STAGE(0);
            asm volatile("s_waitcnt vmcnt(8)" ::: "memory");
        } else {
            asm volatile("s_waitcnt vmcnt(0)" ::: "memory");
        }
        BAR();
        __builtin_amdgcn_s_setprio(1);
        COMPUTE(BUF_BYTES);
        __builtin_amdgcn_s_setprio(0);
        BAR();
    }
    __syncthreads();    // all waves done reading buffers before epilogue reuse

    // ---- epilogue: per-wave LDS transpose to (co, fx), coalesced stores ----
    float* ob = (float*)(lds + w * 9216);   // [64 co][36 floats pitch] (144B)
    int fy = 2 * (Y0 + r) + py;
    float* outb = out + (((size_t)b * COUT + cb * 64) * 128 + fy) * 128;
#pragma unroll
    for (int mt = 0; mt < 2; ++mt)
#pragma unroll
        for (int hh = 0; hh < 2; ++hh) {
            int fx0 = mt * 64 + hh * 32;
#pragma unroll
            for (int nt = 0; nt < 2; ++nt)
#pragma unroll
                for (int j = 0; j < 8; ++j) {
                    int reg = hh * 8 + j;
                    int Xl = (j & 3) + ((j >> 2) << 3) + (hf << 2);
                    int cw = nt * 32 + l31;
                    f32x2 v;
                    v.x = acc[0][mt][nt][reg];
                    v.y = acc[1][mt][nt][reg];
                    *(f32x2*)(ob + cw * 36 + Xl * 2) = v;
                }
            asm volatile("s_waitcnt lgkmcnt(0)" ::: "memory");
#pragma unroll
            for (int rr = 0; rr < 2; ++rr) {
                int co_r = (lane >> 1) + rr * 32;
                const float* srcp = ob + co_r * 36 + (lane & 1) * 16;
                float* dstp = outb + (size_t)co_r * 16384 + fx0 + (lane & 1) * 16;
#pragma unroll
                for (int q = 0; q < 4; ++q)
                    *(f32x4*)(dstp + q * 4) = *(const f32x4*)(srcp + q * 4);
            }
            asm volatile("s_waitcnt lgkmcnt(0)" ::: "memory");
        }
#undef STAGE
#undef BAR
#undef COMPUTE
}

// ---------------------------------------------------------------------------
// FALLBACK (round-1 fp32 path) if ws_size too small for the MFMA pipeline
// ---------------------------------------------------------------------------
__global__ __launch_bounds__(256)
void fused_upconv_blur_kernel(const float* __restrict__ input,
                              const float* __restrict__ weight,
                              const float* __restrict__ s,
                              const float* __restrict__ demod,
                              float* __restrict__ out) {
    const int t = threadIdx.x;
    const int tY = blockIdx.x >> 2, tX = blockIdx.x & 3;
    const int cob = blockIdx.y * 4;
    const int b = blockIdx.z;
    const int Y0 = tY * 16, X0 = tX * 16;
    __shared__ __attribute__((aligned(16))) float patch[19][20];
    __shared__ __attribute__((aligned(16))) float wsm[4][12];
    __shared__ __attribute__((aligned(16))) float out1[36][37];
    __shared__ __attribute__((aligned(16))) float tmpb[35][33];
    const float scale = 0.014731391274719739f;
    float dmv[4];
#pragma unroll
    for (int c = 0; c < 4; ++c) dmv[c] = demod[b * COUT + cob + c] * scale;
    float a0[4][4], a1[4][4];
#pragma unroll
    for (int c = 0; c < 4; ++c)
#pragma unroll
        for (int q = 0; q < 4; ++q) { a0[c][q] = 0.f; a1[c][q] = 0.f; }
    const int p0 = t, p1 = t + 256;
    const int qY0 = p0 / 18, qX0 = p0 % 18;
    const int qY1s = p1 / 18, qX1 = p1 % 18;
    const bool act1 = (p1 < 324);
    const int qY1 = act1 ? qY1s : 0;
    const float* inb = input + (size_t)b * CIN * HH * WW;
    const float* sb = s + (size_t)b * CIN;
    for (int ci = 0; ci < CIN; ++ci) {
        const float* inc = inb + (size_t)ci * (HH * WW);
        for (int idx = t; idx < 361; idx += 256) {
            int rr = idx / 19, cc = idx - rr * 19;
            int gr = Y0 - 2 + rr, gc = X0 - 2 + cc;
            float v = 0.f;
            if ((unsigned)gr < 64u && (unsigned)gc < 64u) v = inc[gr * 64 + gc];
            patch[rr][cc] = v;
        }
        if (t < 36) {
            int c = t / 9, k = t - c * 9;
            wsm[c][k] = weight[((size_t)(cob + c) * CIN + ci) * 9 + k] * sb[ci] * dmv[c];
        }
        __syncthreads();
        const float i00a = patch[qY0][qX0], i01a = patch[qY0][qX0 + 1];
        const float i10a = patch[qY0 + 1][qX0], i11a = patch[qY0 + 1][qX0 + 1];
        float i00b = 0.f, i01b = 0.f, i10b = 0.f, i11b = 0.f;
        if (act1) {
            i00b = patch[qY1][qX1]; i01b = patch[qY1][qX1 + 1];
            i10b = patch[qY1 + 1][qX1]; i11b = patch[qY1 + 1][qX1 + 1];
        }
#pragma unroll
        for (int c = 0; c < 4; ++c) {
            const float4 wA = *(const float4*)&wsm[c][0];
            const float4 wB = *(const float4*)&wsm[c][4];
            const float w8v = wsm[c][8];
            a0[c][0] += i11a * wA.x + i10a * wA.z + i01a * wB.z + i00a * w8v;
            a0[c][1] += i11a * wA.y + i01a * wB.w;
            a0[c][2] += i11a * wA.w + i10a * wB.y;
            a0[c][3] += i11a * wB.x;
            if (act1) {
                a1[c][0] += i11b * wA.x + i10b * wA.z + i01b * wB.z + i00b * w8v;
                a1[c][1] += i11b * wA.y + i01b * wB.w;
                a1[c][2] += i11b * wA.w + i10b * wB.y;
                a1[c][3] += i11b * wB.x;
            }
        }
        __syncthreads();
    }
    const size_t out_base = ((size_t)b * COUT + cob) * 128 * 128;
    for (int c = 0; c < 4; ++c) {
        __syncthreads();
        out1[2 * qY0][2 * qX0] = a0[c][0];
        out1[2 * qY0][2 * qX0 + 1] = a0[c][1];
        out1[2 * qY0 + 1][2 * qX0] = a0[c][2];
        out1[2 * qY0 + 1][2 * qX0 + 1] = a0[c][3];
        if (act1) {
            out1[2 * qY1][2 * qX1] = a1[c][0];
            out1[2 * qY1][2 * qX1 + 1] = a1[c][1];
            out1[2 * qY1 + 1][2 * qX1] = a1[c][2];
            out1[2 * qY1 + 1][2 * qX1 + 1] = a1[c][3];
        }
        __syncthreads();
        for (int idx = t; idx < 35 * 32; idx += 256) {
            int rr = idx >> 5, x = idx & 31;
            tmpb[rr][x] = 0.25f * (out1[rr + 1][x + 1] + out1[rr + 1][x + 4])
                        + 0.75f * (out1[rr + 1][x + 2] + out1[rr + 1][x + 3]);
        }
        __syncthreads();
        float* outc = out + out_base + (size_t)c * 128 * 128;
        for (int idx = t; idx < 1024; idx += 256) {
            int oy = idx >> 5, x = idx & 31;
            float v = 0.25f * (tmpb[oy][x] + tmpb[oy + 3][x])
                    + 0.75f * (tmpb[oy + 1][x] + tmpb[oy + 2][x]);
            outc[(size_t)(2 * Y0 + oy) * 128 + (2 * X0 + x)] = v;
        }
    }
}

// ---------------------------------------------------------------------------
extern "C" void kernel_launch(void* const* d_in, const int* in_sizes, int n_in,
                              void* d_out, int out_size, void* d_ws, size_t ws_size,
                              hipStream_t stream) {
    const float* input      = (const float*)d_in[0];
    const float* style      = (const float*)d_in[1];
    const float* weight     = (const float*)d_in[2];
    const float* mod_weight = (const float*)d_in[3];
    const float* mod_bias   = (const float*)d_in[4];
    float* out = (float*)d_out;

    // ws layout: s(16KB) | dm(8KB) | zeropage(1KB)+pad | in_t bf16 | W4g bf16
    const size_t OFF_S = 0, OFF_DM = 16384, OFF_ZP = 24576, OFF_INT = 32768;
    const size_t OFF_W4 = OFF_INT + (size_t)BATCH * 64 * 64 * CIN * 2;      // 33587200
    const size_t WS_NEEDED = OFF_W4 + (size_t)BATCH * 4 * 9 * COUT * CIN * 2; // 109084672

    float* s_buf  = (float*)((char*)d_ws + OFF_S);
    float* dm_buf = (float*)((char*)d_ws + OFF_DM);
    uint4* zp     = (uint4*)((char*)d_ws + OFF_ZP);

    style_mod_kernel<<<BATCH * CIN, 64, 0, stream>>>(style, mod_weight, mod_bias, s_buf, zp);
    demod_kernel<<<BATCH * COUT, 256, 0, stream>>>(weight, s_buf, dm_buf);

    if (ws_size >= WS_NEEDED) {
        unsigned short* in_t = (unsigned short*)((char*)d_ws + OFF_INT);
        unsigned short* W4g  = (unsigned short*)((char*)d_ws + OFF_W4);
        transpose_kernel<<<BATCH * 64, 256, 0, stream>>>(input, in_t);
        fold_kernel<<<BATCH * (COUT / 2), 256, 0, stream>>>(weight, s_buf, dm_buf, W4g);
        conv_kernel<<<512, 512, 0, stream>>>(in_t, W4g, zp, out);
    } else {
        fused_upconv_blur_kernel<<<dim3(16, COUT / 4, BATCH), 256, 0, stream>>>(
            input, weight, s_buf, dm_buf, out);
    }
}

// Round 6
// 510.928 us; speedup vs baseline: 1.0761x; 1.0164x over previous
//
#include <hip/hip_runtime.h>
#include <math.h>

#define BATCH 8
#define CIN 512
#define COUT 256
#define HH 64
#define WW 64
#define WDIM 512

typedef __attribute__((ext_vector_type(8))) short bf16x8;
typedef __attribute__((ext_vector_type(16))) float f32x16;
typedef __attribute__((ext_vector_type(2))) float f32x2;
typedef __attribute__((ext_vector_type(4))) float f32x4;

__device__ __forceinline__ unsigned short f2bf(float f) {
    union { float f; unsigned u; } v; v.f = f;
    unsigned r = v.u + 0x7FFFu + ((v.u >> 16) & 1u);
    return (unsigned short)(r >> 16);
}

// ---------------------------------------------------------------------------
// PREP kernel: fuses transpose (blocks 0..511) + style_mod (blocks 512..1535).
//
// transpose part: input [b][ci][y][x] fp32 -> in_t [b][y][x][ci] bf16,
//   float4-vectorized global loads (32 iters vs 128 scalar), same LDS
//   swizzle and identical output layout (conv DMA contract unchanged).
// style part: s[b,ci] = style @ (mod_weight/sqrt(512)).T + mod_bias,
//   4 (b,ci) rows per block, one per wave. Block 512 also zeros zeropage.
// ---------------------------------------------------------------------------
__global__ __launch_bounds__(256)
void prep_kernel(const float* __restrict__ input,
                 const float* __restrict__ style,
                 const float* __restrict__ mod_weight,
                 const float* __restrict__ mod_bias,
                 unsigned short* __restrict__ in_t,
                 float* __restrict__ s,
                 uint4* __restrict__ zp) {
    int L = blockIdx.x;
    int t = threadIdx.x;
    __shared__ unsigned short tile[64 * 512];
    if (L < 512) {
        int b = L >> 6, y = L & 63;
        int xq = t & 15, cw = t >> 4;       // xq: x-quad 0..15, cw: ci sub 0..15
        const float* src = input + ((size_t)b * CIN * 64 + y) * 64;
        for (int it = 0; it < 32; ++it) {
            int ci = it * 16 + cw;
            float4 v4 = *(const float4*)(src + (size_t)ci * 4096 + xq * 4);
            float vv[4] = {v4.x, v4.y, v4.z, v4.w};
#pragma unroll
            for (int i = 0; i < 4; ++i) {
                int x = xq * 4 + i;
                tile[x * 512 + ((((ci >> 3) ^ (x & 7)) << 3) | (ci & 7))] = f2bf(vv[i]);
            }
        }
        __syncthreads();
        int wv = t >> 6, lane = t & 63;
        unsigned short* dst = in_t + (((size_t)b * 64 + y) * 64) * 512;
        for (int it = 0; it < 16; ++it) {
            int xx = it * 4 + wv;
            uint4 v = *(const uint4*)&tile[xx * 512 + ((lane ^ (xx & 7)) << 3)];
            *(uint4*)(dst + (size_t)xx * 512 + lane * 8) = v;
        }
    } else {
        if (L == 512 && t < 64) zp[t] = make_uint4(0u, 0u, 0u, 0u);
        int q = (L - 512) * 4 + (t >> 6);   // (b,ci) index, 0..4095
        int b = q >> 9, ci = q & 511;
        int lane = t & 63;
        const float* mw = mod_weight + (size_t)ci * WDIM;
        const float* st = style + (size_t)b * WDIM;
        float acc = 0.f;
        for (int d = lane; d < WDIM; d += 64) acc += mw[d] * st[d];
        for (int off = 32; off > 0; off >>= 1) acc += __shfl_down(acc, off);
        if (lane == 0) s[q] = acc * 0.04419417382415922f + mod_bias[ci];
    }
}

// ---------------------------------------------------------------------------
// FOLD kernel (now also computes demod in-block): blur folded into modulated
// weights. W4g[b][pp=py*2+px][tap][co][ci] bf16 — layout unchanged.
// Block = (b, co-pair); thread = (co_local = t>>7, 4 consecutive ci).
// Each thread computes v = scale*w*s for its 4ci x 9 taps, block-half
// reduces sum(v^2) -> demod = rsqrt(sum + 1e-8), then folds blur and writes
// coalesced ushort4 stores. Eliminates the separate demod kernel and one
// full pass over weight.
// ---------------------------------------------------------------------------
__global__ __launch_bounds__(256)
void fold_kernel(const float* __restrict__ weight,
                 const float* __restrict__ s,
                 unsigned short* __restrict__ W4g) {
    int b = blockIdx.x >> 7;            // 8 batches
    int cop = blockIdx.x & 127;         // 128 co-pairs
    int t = threadIdx.x;
    int co = cop * 2 + (t >> 7);
    int ci0 = (t & 127) * 4;
    const float scale = 0.014731391274719739f;   // 1/sqrt(512*9)

    const float* wp = weight + ((size_t)co * CIN + ci0) * 9;
    float wm[4][9];
    float sq = 0.f;
#pragma unroll
    for (int c = 0; c < 4; ++c) {
        float m = scale * s[b * CIN + ci0 + c];
#pragma unroll
        for (int k = 0; k < 9; ++k) {
            float v = wp[c * 9 + k] * m;
            wm[c][k] = v;
            sq += v * v;
        }
    }
    // block-half reduction (threads 0..127 -> co, 128..255 -> co+1)
    __shared__ float red[256];
    red[t] = sq;
    __syncthreads();
    if ((t & 127) < 64) {
        float v = red[t] + red[t + 64];
        for (int off = 32; off > 0; off >>= 1) v += __shfl_down(v, off);
        if ((t & 63) == 0) red[t] = v;      // red[0], red[128]
    }
    __syncthreads();
    float dmv = rsqrtf(red[t & 128] + 1e-8f);
#pragma unroll
    for (int c = 0; c < 4; ++c)
#pragma unroll
        for (int k = 0; k < 9; ++k) wm[c][k] *= dmv;

    // T[p][d'][wi]: blur folded per-dim transfer (d' = -1..1 -> 0..2)
    const float T[2][3][3] = {
        {{0.f, .25f, .75f}, {.75f, .75f, .25f}, {.25f, 0.f, 0.f}},
        {{0.f, 0.f, .25f}, {.25f, .75f, .75f}, {.75f, .25f, 0.f}}};

#pragma unroll
    for (int py = 0; py < 2; ++py)
#pragma unroll
        for (int px = 0; px < 2; ++px)
#pragma unroll
            for (int dy = 0; dy < 3; ++dy)
#pragma unroll
                for (int dx = 0; dx < 3; ++dx) {
                    unsigned short pk[4];
#pragma unroll
                    for (int c = 0; c < 4; ++c) {
                        float acc = 0.f;
#pragma unroll
                        for (int ky = 0; ky < 3; ++ky)
#pragma unroll
                            for (int kx = 0; kx < 3; ++kx)
                                acc += T[py][dy][ky] * T[px][dx][kx] * wm[c][ky * 3 + kx];
                        pk[c] = f2bf(acc);
                    }
                    size_t off = ((((size_t)(b * 4 + py * 2 + px) * 9 + dy * 3 + dx) * COUT + co) * CIN) + ci0;
                    ushort4 v; v.x = pk[0]; v.y = pk[1]; v.z = pk[2]; v.w = pk[3];
                    *(ushort4*)(W4g + off) = v;
                }
}

// ---------------------------------------------------------------------------
// Kernel 5: MFMA conv, 512 threads / 8 waves. wave w = output row r (8 rows).
// Each wave computes BOTH px: acc[2px][2mt][2nt] -> 6 LDS reads per 8 MFMA.
// Double-buffered global_load_lds staging, 2-phase counted-vmcnt schedule.
// (Unchanged from round 4/5 — conv is at its LDS/MFMA serialization plateau.)
// ---------------------------------------------------------------------------
#define BUF_BYTES 65536                 // 4096 slots * 16B
#define LDS_W0 21120                    // 1320 * 16
#define LDS_TOTAL2 (2 * BUF_BYTES)      // 131072

__global__ __launch_bounds__(512, 2)
void conv_kernel(const unsigned short* __restrict__ in_t,
                 const unsigned short* __restrict__ W4g,
                 const uint4* __restrict__ zeropage,
                 float* __restrict__ out) {
    __shared__ char lds[LDS_TOTAL2];
    int L = blockIdx.x;                 // 512 blocks
    // XCD swizzle: 8 Y-siblings of a (b,py,cb) group spaced 8 apart -> same XCD
    int g = ((L >> 6) << 3) | (L & 7);
    int sbq = (L >> 3) & 7;
    int b = g >> 3, rgrp = g & 7;
    int py = rgrp >> 2, cb = rgrp & 3;
    int Y0 = sbq * 8;
    int t = threadIdx.x, w = t >> 6, lane = t & 63;
    int l31 = lane & 31, hf = lane >> 5;
    int r = w;                          // wave owns output row Y0 + r

    const unsigned short* inb = in_t + (size_t)b * 64 * 64 * 512;
    const unsigned short* wb = W4g + ((size_t)(b * 4 + py * 2)) * 9 * COUT * CIN;

    // per-thread static task -> 8 global byte pointers (advance 32B per chunk)
    const char* gp[8];
#pragma unroll
    for (int k = 0; k < 8; ++k) {
        int task = t + (k << 9);
        const void* p;
        if (task < 1320) {
            int row = task / 132;
            int rem = task - row * 132;
            int h = rem / 66;
            int cell = rem - h * 66;
            int y = Y0 - 1 + row, x = cell - 1;
            p = ((unsigned)y < 64u && (unsigned)x < 64u)
                    ? (const void*)(inb + ((size_t)(y * 64 + x) * 512 + h * 8))
                    : (const void*)zeropage;
        } else if (task < 3624) {
            int wt = task - 1320;
            int co = wt & 63, h = (wt >> 6) & 1, tp = wt >> 7;
            p = (const void*)(wb + (size_t)tp * (COUT * CIN) +
                              (size_t)(cb * 64 + co) * CIN + h * 8);
        } else {
            p = (const void*)zeropage;
        }
        gp[k] = (const char*)p;
    }

    f32x16 acc[2][2][2];                // [px][mt][nt]
#pragma unroll
    for (int px = 0; px < 2; ++px)
#pragma unroll
        for (int mt = 0; mt < 2; ++mt)
#pragma unroll
            for (int nt = 0; nt < 2; ++nt) acc[px][mt][nt] = (f32x16)0.f;

#define STAGE(BUFOFF)                                                             \
    {                                                                             \
        char* lb = lds + (BUFOFF) + (w << 10);                                    \
        _Pragma("unroll")                                                         \
        for (int k = 0; k < 8; ++k) {                                             \
            __builtin_amdgcn_global_load_lds(                                     \
                (const __attribute__((address_space(1))) void*)gp[k],             \
                (__attribute__((address_space(3))) void*)(lb + (k << 13)),        \
                16, 0, 0);                                                        \
            gp[k] += 32;                                                          \
        }                                                                         \
    }

#define BAR()                                  \
    {                                          \
        asm volatile("" ::: "memory");         \
        __builtin_amdgcn_s_barrier();          \
        asm volatile("" ::: "memory");         \
    }

#define SGB __builtin_amdgcn_sched_group_barrier

    // 2-deep tap pipeline. Reg sets indexed by tap parity (compile-time under
    // full unroll -> stays in registers, rule #20).
#define COMPUTE(BUFOFF)                                                             \
    {                                                                               \
        const char* Bp = lds + (BUFOFF);                                            \
        bf16x8 Ra0[2], Ra1[2], Rb[2][2][2];                                         \
        {   /* prologue: tap 0 -> parity 0 */                                       \
            int cell0 = ((1 + r - 1) * 2 + hf) * 66 + (1 + l31 - 1);                \
            Ra0[0] = *(const bf16x8*)(Bp + (cell0 << 4));                           \
            Ra1[0] = *(const bf16x8*)(Bp + ((cell0 + 32) << 4));                    \
            _Pragma("unroll")                                                       \
            for (int px = 0; px < 2; ++px) {                                        \
                int tp = px * 9;                                                    \
                const char* Wp = Bp + LDS_W0 + (((tp * 2 + hf) * 64 + l31) << 4);   \
                Rb[0][px][0] = *(const bf16x8*)(Wp);                                \
                Rb[0][px][1] = *(const bf16x8*)(Wp + 512);                          \
            }                                                                       \
        }                                                                           \
        SGB(0x100, 6, 0);                       /* [R0] */                          \
        _Pragma("unroll")                                                           \
        for (int tap = 0; tap < 9; ++tap) {                                         \
            const int cur = tap & 1, nxt = cur ^ 1;                                 \
            if (tap < 8) {                                                          \
                const int tn = tap + 1;                                             \
                const int dy = tn / 3 - 1, dx = tn % 3 - 1;                         \
                int cell0 = ((1 + r + dy) * 2 + hf) * 66 + (1 + l31 + dx);          \
                Ra0[nxt] = *(const bf16x8*)(Bp + (cell0 << 4));                     \
                Ra1[nxt] = *(const bf16x8*)(Bp + ((cell0 + 32) << 4));              \
                _Pragma("unroll")                                                   \
                for (int px = 0; px < 2; ++px) {                                    \
                    int tp = px * 9 + tn;                                           \
                    const char* Wp = Bp + LDS_W0 +                                  \
                                     (((tp * 2 + hf) * 64 + l31) << 4);             \
                    Rb[nxt][px][0] = *(const bf16x8*)(Wp);                          \
                    Rb[nxt][px][1] = *(const bf16x8*)(Wp + 512);                    \
                }                                                                   \
                SGB(0x100, 6, 0);               /* [R(t+1)] */                      \
            }                                                                       \
            _Pragma("unroll")                                                       \
            for (int px = 0; px < 2; ++px) {                                        \
                acc[px][0][0] = __builtin_amdgcn_mfma_f32_32x32x16_bf16(            \
                    Ra0[cur], Rb[cur][px][0], acc[px][0][0], 0, 0, 0);              \
                acc[px][0][1] = __builtin_amdgcn_mfma_f32_32x32x16_bf16(            \
                    Ra0[cur], Rb[cur][px][1], acc[px][0][1], 0, 0, 0);              \
                acc[px][1][0] = __builtin_amdgcn_mfma_f32_32x32x16_bf16(            \
                    Ra1[cur], Rb[cur][px][0], acc[px][1][0], 0, 0, 0);              \
                acc[px][1][1] = __builtin_amdgcn_mfma_f32_32x32x16_bf16(            \
                    Ra1[cur], Rb[cur][px][1], acc[px][1][1], 0, 0, 0);              \
            }                                                                       \
            SGB(0x8, 8, 0);                     /* [M(t)] */                        \
        }                                                                           \
    }

    STAGE(0);                                   // chunk 0 -> buf0
#pragma unroll 1
    for (int cc = 0; cc < 16; ++cc) {
        // phase A: stage chunk 2cc+1 -> buf1, compute chunk 2cc from buf0
        STAGE(BUF_BYTES);
        asm volatile("s_waitcnt vmcnt(8)" ::: "memory");
        BAR();
        __builtin_amdgcn_s_setprio(1);
        COMPUTE(0);
        __builtin_amdgcn_s_setprio(0);
        BAR();
        // phase B: stage chunk 2cc+2 -> buf0 (if any), compute chunk 2cc+1
        if (cc < 15) {
            STAGE(0);
            asm volatile("s_waitcnt vmcnt(8)" ::: "memory");
        } else {
            asm volatile("s_waitcnt vmcnt(0)" ::: "memory");
        }
        BAR();
        __builtin_amdgcn_s_setprio(1);
        COMPUTE(BUF_BYTES);
        __builtin_amdgcn_s_setprio(0);
        BAR();
    }
    __syncthreads();    // all waves done reading buffers before epilogue reuse

    // ---- epilogue: per-wave LDS transpose to (co, fx), coalesced stores ----
    float* ob = (float*)(lds + w * 9216);   // [64 co][36 floats pitch] (144B)
    int fy = 2 * (Y0 + r) + py;
    float* outb = out + (((size_t)b * COUT + cb * 64) * 128 + fy) * 128;
#pragma unroll
    for (int mt = 0; mt < 2; ++mt)
#pragma unroll
        for (int hh = 0; hh < 2; ++hh) {
            int fx0 = mt * 64 + hh * 32;
#pragma unroll
            for (int nt = 0; nt < 2; ++nt)
#pragma unroll
                for (int j = 0; j < 8; ++j) {
                    int reg = hh * 8 + j;
                    int Xl = (j & 3) + ((j >> 2) << 3) + (hf << 2);
                    int cw = nt * 32 + l31;
                    f32x2 v;
                    v.x = acc[0][mt][nt][reg];
                    v.y = acc[1][mt][nt][reg];
                    *(f32x2*)(ob + cw * 36 + Xl * 2) = v;
                }
            asm volatile("s_waitcnt lgkmcnt(0)" ::: "memory");
#pragma unroll
            for (int rr = 0; rr < 2; ++rr) {
                int co_r = (lane >> 1) + rr * 32;
                const float* srcp = ob + co_r * 36 + (lane & 1) * 16;
                float* dstp = outb + (size_t)co_r * 16384 + fx0 + (lane & 1) * 16;
#pragma unroll
                for (int q = 0; q < 4; ++q)
                    *(f32x4*)(dstp + q * 4) = *(const f32x4*)(srcp + q * 4);
            }
            asm volatile("s_waitcnt lgkmcnt(0)" ::: "memory");
        }
#undef STAGE
#undef BAR
#undef COMPUTE
}

// ---------------------------------------------------------------------------
// FALLBACK path kernels (only used if ws_size too small for MFMA pipeline)
// ---------------------------------------------------------------------------
__global__ __launch_bounds__(64)
void style_mod_kernel(const float* __restrict__ style,
                      const float* __restrict__ mod_weight,
                      const float* __restrict__ mod_bias,
                      float* __restrict__ s) {
    int idx = blockIdx.x;
    int b = idx / CIN, ci = idx % CIN;
    int lane = threadIdx.x;
    const float* mw = mod_weight + (size_t)ci * WDIM;
    const float* st = style + (size_t)b * WDIM;
    float acc = 0.f;
    for (int d = lane; d < WDIM; d += 64) acc += mw[d] * st[d];
    for (int off = 32; off > 0; off >>= 1) acc += __shfl_down(acc, off);
    if (lane == 0) s[idx] = acc * 0.04419417382415922f + mod_bias[ci];
}

__global__ __launch_bounds__(256)
void demod_kernel(const float* __restrict__ weight,
                  const float* __restrict__ s,
                  float* __restrict__ demod) {
    int b = blockIdx.x / COUT, co = blockIdx.x % COUT;
    int t = threadIdx.x;
    const float scale = 0.014731391274719739f;
    const float* wco = weight + (size_t)co * CIN * 9;
    const float* sb = s + (size_t)b * CIN;
    float acc = 0.f;
    for (int i = t; i < CIN * 9; i += 256) {
        int ci = i / 9;
        float v = scale * wco[i] * sb[ci];
        acc += v * v;
    }
    __shared__ float red[256];
    red[t] = acc;
    __syncthreads();
    if (t < 128) red[t] += red[t + 128];
    __syncthreads();
    if (t < 64) {
        float v = red[t] + red[t + 64];
        for (int off = 32; off > 0; off >>= 1) v += __shfl_down(v, off);
        if (t == 0) demod[blockIdx.x] = rsqrtf(v + 1e-8f);
    }
}

__global__ __launch_bounds__(256)
void fused_upconv_blur_kernel(const float* __restrict__ input,
                              const float* __restrict__ weight,
                              const float* __restrict__ s,
                              const float* __restrict__ demod,
                              float* __restrict__ out) {
    const int t = threadIdx.x;
    const int tY = blockIdx.x >> 2, tX = blockIdx.x & 3;
    const int cob = blockIdx.y * 4;
    const int b = blockIdx.z;
    const int Y0 = tY * 16, X0 = tX * 16;
    __shared__ __attribute__((aligned(16))) float patch[19][20];
    __shared__ __attribute__((aligned(16))) float wsm[4][12];
    __shared__ __attribute__((aligned(16))) float out1[36][37];
    __shared__ __attribute__((aligned(16))) float tmpb[35][33];
    const float scale = 0.014731391274719739f;
    float dmv[4];
#pragma unroll
    for (int c = 0; c < 4; ++c) dmv[c] = demod[b * COUT + cob + c] * scale;
    float a0[4][4], a1[4][4];
#pragma unroll
    for (int c = 0; c < 4; ++c)
#pragma unroll
        for (int q = 0; q < 4; ++q) { a0[c][q] = 0.f; a1[c][q] = 0.f; }
    const int p0 = t, p1 = t + 256;
    const int qY0 = p0 / 18, qX0 = p0 % 18;
    const int qY1s = p1 / 18, qX1 = p1 % 18;
    const bool act1 = (p1 < 324);
    const int qY1 = act1 ? qY1s : 0;
    const float* inb = input + (size_t)b * CIN * HH * WW;
    const float* sb = s + (size_t)b * CIN;
    for (int ci = 0; ci < CIN; ++ci) {
        const float* inc = inb + (size_t)ci * (HH * WW);
        for (int idx = t; idx < 361; idx += 256) {
            int rr = idx / 19, cc = idx - rr * 19;
            int gr = Y0 - 2 + rr, gc = X0 - 2 + cc;
            float v = 0.f;
            if ((unsigned)gr < 64u && (unsigned)gc < 64u) v = inc[gr * 64 + gc];
            patch[rr][cc] = v;
        }
        if (t < 36) {
            int c = t / 9, k = t - c * 9;
            wsm[c][k] = weight[((size_t)(cob + c) * CIN + ci) * 9 + k] * sb[ci] * dmv[c];
        }
        __syncthreads();
        const float i00a = patch[qY0][qX0], i01a = patch[qY0][qX0 + 1];
        const float i10a = patch[qY0 + 1][qX0], i11a = patch[qY0 + 1][qX0 + 1];
        float i00b = 0.f, i01b = 0.f, i10b = 0.f, i11b = 0.f;
        if (act1) {
            i00b = patch[qY1][qX1]; i01b = patch[qY1][qX1 + 1];
            i10b = patch[qY1 + 1][qX1]; i11b = patch[qY1 + 1][qX1 + 1];
        }
#pragma unroll
        for (int c = 0; c < 4; ++c) {
            const float4 wA = *(const float4*)&wsm[c][0];
            const float4 wB = *(const float4*)&wsm[c][4];
            const float w8v = wsm[c][8];
            a0[c][0] += i11a * wA.x + i10a * wA.z + i01a * wB.z + i00a * w8v;
            a0[c][1] += i11a * wA.y + i01a * wB.w;
            a0[c][2] += i11a * wA.w + i10a * wB.y;
            a0[c][3] += i11a * wB.x;
            if (act1) {
                a1[c][0] += i11b * wA.x + i10b * wA.z + i01b * wB.z + i00b * w8v;
                a1[c][1] += i11b * wA.y + i01b * wB.w;
                a1[c][2] += i11b * wA.w + i10b * wB.y;
                a1[c][3] += i11b * wB.x;
            }
        }
        __syncthreads();
    }
    const size_t out_base = ((size_t)b * COUT + cob) * 128 * 128;
    for (int c = 0; c < 4; ++c) {
        __syncthreads();
        out1[2 * qY0][2 * qX0] = a0[c][0];
        out1[2 * qY0][2 * qX0 + 1] = a0[c][1];
        out1[2 * qY0 + 1][2 * qX0] = a0[c][2];
        out1[2 * qY0 + 1][2 * qX0 + 1] = a0[c][3];
        if (act1) {
            out1[2 * qY1][2 * qX1] = a1[c][0];
            out1[2 * qY1][2 * qX1 + 1] = a1[c][1];
            out1[2 * qY1 + 1][2 * qX1] = a1[c][2];
            out1[2 * qY1 + 1][2 * qX1 + 1] = a1[c][3];
        }
        __syncthreads();
        for (int idx = t; idx < 35 * 32; idx += 256) {
            int rr = idx >> 5, x = idx & 31;
            tmpb[rr][x] = 0.25f * (out1[rr + 1][x + 1] + out1[rr + 1][x + 4])
                        + 0.75f * (out1[rr + 1][x + 2] + out1[rr + 1][x + 3]);
        }
        __syncthreads();
        float* outc = out + out_base + (size_t)c * 128 * 128;
        for (int idx = t; idx < 1024; idx += 256) {
            int oy = idx >> 5, x = idx & 31;
            float v = 0.25f * (tmpb[oy][x] + tmpb[oy + 3][x])
                    + 0.75f * (tmpb[oy + 1][x] + tmpb[oy + 2][x]);
            outc[(size_t)(2 * Y0 + oy) * 128 + (2 * X0 + x)] = v;
        }
    }
}

// ---------------------------------------------------------------------------
extern "C" void kernel_launch(void* const* d_in, const int* in_sizes, int n_in,
                              void* d_out, int out_size, void* d_ws, size_t ws_size,
                              hipStream_t stream) {
    const float* input      = (const float*)d_in[0];
    const float* style      = (const float*)d_in[1];
    const float* weight     = (const float*)d_in[2];
    const float* mod_weight = (const float*)d_in[3];
    const float* mod_bias   = (const float*)d_in[4];
    float* out = (float*)d_out;

    // ws layout: s(16KB) | dm(8KB) | zeropage(1KB)+pad | in_t bf16 | W4g bf16
    const size_t OFF_S = 0, OFF_DM = 16384, OFF_ZP = 24576, OFF_INT = 32768;
    const size_t OFF_W4 = OFF_INT + (size_t)BATCH * 64 * 64 * CIN * 2;      // 33587200
    const size_t WS_NEEDED = OFF_W4 + (size_t)BATCH * 4 * 9 * COUT * CIN * 2; // 109084672

    float* s_buf  = (float*)((char*)d_ws + OFF_S);
    float* dm_buf = (float*)((char*)d_ws + OFF_DM);
    uint4* zp     = (uint4*)((char*)d_ws + OFF_ZP);

    if (ws_size >= WS_NEEDED) {
        unsigned short* in_t = (unsigned short*)((char*)d_ws + OFF_INT);
        unsigned short* W4g  = (unsigned short*)((char*)d_ws + OFF_W4);
        prep_kernel<<<1536, 256, 0, stream>>>(input, style, mod_weight, mod_bias,
                                              in_t, s_buf, zp);
        fold_kernel<<<BATCH * (COUT / 2), 256, 0, stream>>>(weight, s_buf, W4g);
        conv_kernel<<<512, 512, 0, stream>>>(in_t, W4g, zp, out);
    } else {
        style_mod_kernel<<<BATCH * CIN, 64, 0, stream>>>(style, mod_weight, mod_bias, s_buf);
        demod_kernel<<<BATCH * COUT, 256, 0, stream>>>(weight, s_buf, dm_buf);
        fused_upconv_blur_kernel<<<dim3(16, COUT / 4, BATCH), 256, 0, stream>>>(
            input, weight, s_buf, dm_buf, out);
    }
}